// Round 6
// baseline (210.416 us; speedup 1.0000x reference)
//
#include <hip/hip_runtime.h>

// MLSA-style multi-stage time-varying FIR.
// y = (sum_{n=0..20} F^n x / n!) * exp(lerp(mc[...,0]))
// F: xn[t] = sum_{d=1..49} lerp_t(mc[:, :, d]) * xa[t-d]
//
// Round-5: de-serialize LDS and VALU phases. Rounds 2-4 showed the pipes run
// ~60%/~60% but SERIALIZED (dur ~= V+L per stage): the per-stage barrier puts
// all 12 waves into an LDS storm (window+tap reads), then an all-FMA phase.
//  - window groups are now loaded just-in-time inside the unrolled tap loop
//    (group g at p = 22-2g, 2 p-steps of prefetch): LDS reads interleave with
//    FMAs instead of clumping; A's live range drops 52 -> ~16 regs.
//  - taps for lags 1..40 live in registers (NTC=20, 80 VGPR); only lags
//    41..49 read from LDS per stage. LDS wave-inst/stage: 30 -> 20.
//  - flat sample map (pair remap of r3/r4 falsified: conflicts track wave
//    count, not lane stride).

#define FO    49      // filter order (lags 1..49)
#define FP    80      // frame period
#define NST   20      // Taylor stages
#define NB    8       // batch
#define TT    160000  // samples per batch row
#define NFR   2000    // frames
#define NC    50      // coeffs per frame
#define HALO  1024    // left halo (>= 20*49=980)
#define NT    768     // threads per block (12 waves)
#define RPT   8       // samples per thread (8 | 80 -> thread stays in 1 frame)
#define EE    6144    // NT*RPT extended region
#define TOUT  5120    // EE - HALO outputs per tile
#define TILES 32      // TT / TOUT coverage (32*5120 = 163840 >= 160000)
#define PADW  56      // zero pad words in front of data (underrun reach: 52)
#define NFRL  78      // tap rows per block
#define TROW  100     // tap row stride in words (49 float2 + pad; 400B)
#define NTC   20      // tap float4s in registers (lags 1..40); 41..49 from LDS

// 16B-group XOR swizzle. NOTE: swz(g+1) != swz(g)+1 in odd octets -- always
// swizzle each group address individually (round-3 bug).
__device__ __forceinline__ int swz(int g) { return g ^ ((g >> 3) & 7); }

__global__ __launch_bounds__(NT, 3) void mlsa_kernel(
    const float* __restrict__ x, const float* __restrict__ mc,
    float* __restrict__ out) {
  __shared__ __align__(16) float sb0[PADW + EE];
  __shared__ __align__(16) float sb1[PADW + EE];
  __shared__ __align__(16) float taps[NFRL * TROW];

  const int tid  = threadIdx.x;
  const int b    = blockIdx.x >> 5;   // TILES == 32
  const int tile = blockIdx.x & 31;
  const int base = tile * TOUT - HALO;  // global sample index of local 0
  const float* __restrict__ xb  = x + b * TT;
  const float* __restrict__ mcb = mc + b * NFR * NC;

  if (tid < PADW) { sb0[tid] = 0.f; sb1[tid] = 0.f; }

  // Stage x tile into sb0 (stride-1 groups, coalesced; base%4==0, TT%4==0).
  #pragma unroll
  for (int i = 0; i < EE / 4 / NT; ++i) {
    const int q  = i * NT + tid;
    const int t0 = base + q * 4;
    float4 v = make_float4(0.f, 0.f, 0.f, 0.f);
    if (t0 >= 0 && t0 < TT) v = *(const float4*)(xb + t0);
    *(float4*)(sb0 + PADW + 4 * swz(q)) = v;
  }

  // Tap table -> LDS. Row e = frame fb+e; word 2*(d-1) = {c_d, dc_d/FP}.
  const int fb = max(base, 0) / FP;
  for (int idx = tid; idx < NFRL * FO; idx += NT) {
    const int e  = idx / FO;
    const int dm = idx - e * FO;
    const int fa = min(fb + e, NFR - 1);
    const int fn = min(fb + e + 1, NFR - 1);
    const float a0 = mcb[fa * NC + dm + 1];
    const float a1 = mcb[fn * NC + dm + 1];
    *(float2*)(taps + e * TROW + 2 * dm) = make_float2(a0, (a1 - a0) * (1.0f / FP));
  }

  // Flat map: thread owns samples 8*tid .. 8*tid+7 (one frame: 8|80, base%16==0).
  const int g0 = base + RPT * tid;
  const int gc = min(max(g0, 0), TT - 1);
  const int n0 = gc / FP;
  const int fi = n0 - fb;
  const float p0f = (float)(gc - n0 * FP);

  // Window LDS group addresses (each swizzled individually): groups
  // 2*tid-13 .. 2*tid-1 cover words 8*tid-52 .. 8*tid-1; q<0 -> pad region.
  int widx[13];
  #pragma unroll
  for (int i = 0; i < 13; ++i) {
    const int q = 2 * tid - 13 + i;
    widx[i] = (q < 0) ? (PADW + 4 * q) : (PADW + 4 * swz(q));
  }
  const int sidx0 = PADW + 4 * swz(2 * tid);
  const int sidx1 = PADW + 4 * swz(2 * tid + 1);

  // Own 8 samples; xp persists across stages (= prev stage values).
  float xp[RPT];
  #pragma unroll
  for (int k = 0; k < 2; ++k) {
    const int t0 = g0 + 4 * k;
    float4 v = make_float4(0.f, 0.f, 0.f, 0.f);
    if (t0 >= 0 && t0 < TT) v = *(const float4*)(xb + t0);
    xp[4*k] = v.x; xp[4*k+1] = v.y; xp[4*k+2] = v.z; xp[4*k+3] = v.w;
  }
  float y[RPT];
  #pragma unroll
  for (int j = 0; j < RPT; ++j) y[j] = xp[j];

  __syncthreads();

  // Register tap cache: lags 1..2*NTC (=40).
  const float* trow = taps + fi * TROW;
  float4 tr[NTC];
  #pragma unroll
  for (int p = 0; p < NTC; ++p) tr[p] = *(const float4*)(trow + 4 * p);

  const float* rb = sb0;
  float*       wb = sb1;
  #pragma unroll 1
  for (int s = 1; s <= NST; ++s) {
    // A[m] = stage-(s-1) value at word 8*tid-52+m, m = 0..51 (LDS part);
    // words 52..58 come from xp. Groups are loaded just-in-time: iteration p
    // touches LDS words 50-2p .. min(58-2p,51); group g first needed at
    // p = 24-2g, loaded at p = 22-2g (prefetch 2 p-steps ~ 64 FMAs).
    float A[52];
    float acc0[RPT], acc1[RPT];
    #pragma unroll
    for (int j = 0; j < RPT; ++j) { acc0[j] = 0.f; acc1[j] = 0.f; }
    #pragma unroll
    for (int p = 0; p < 25; ++p) {
      if (p == 0) {  // groups 12, 11 up front
        const float4 v12 = *(const float4*)(rb + widx[12]);
        A[48] = v12.x; A[49] = v12.y; A[50] = v12.z; A[51] = v12.w;
        const float4 v11 = *(const float4*)(rb + widx[11]);
        A[44] = v11.x; A[45] = v11.y; A[46] = v11.z; A[47] = v11.w;
      } else if ((p & 1) == 0 && p <= 22) {  // p=2,4,..,22 -> g=10,9,..,0
        const int g = 11 - p / 2;            // compile-time under unroll
        const float4 v = *(const float4*)(rb + widx[g]);
        A[4*g] = v.x; A[4*g+1] = v.y; A[4*g+2] = v.z; A[4*g+3] = v.w;
      }
      float4 tp;
      if (p < NTC) tp = tr[p];
      else         tp = *(const float4*)(trow + 4 * p);  // lags 41..49
      const int d0 = 2 * p + 1, d1 = 2 * p + 2;
      #pragma unroll
      for (int j = 0; j < RPT; ++j) {
        const int ka = 52 + j - d0;
        const float va = (ka < 52) ? A[ka] : xp[ka - 52];
        acc0[j] = fmaf(tp.x, va, acc0[j]);
        acc1[j] = fmaf(tp.y, va, acc1[j]);
        if (d1 <= FO) {
          const int kb = 52 + j - d1;
          const float vb = (kb < 52) ? A[kb] : xp[kb - 52];
          acc0[j] = fmaf(tp.z, vb, acc0[j]);
          acc1[j] = fmaf(tp.w, vb, acc1[j]);
        }
      }
    }
    const float ia = 1.0f / (float)s;
    #pragma unroll
    for (int j = 0; j < RPT; ++j) {
      const float xn = fmaf(p0f + (float)j, acc1[j], acc0[j]) * ia;
      y[j] += xn;
      xp[j] = xn;
    }
    {
      float4 v;
      v.x = xp[0]; v.y = xp[1]; v.z = xp[2]; v.w = xp[3];
      *(float4*)(wb + sidx0) = v;
      v.x = xp[4]; v.y = xp[5]; v.z = xp[6]; v.w = xp[7];
      *(float4*)(wb + sidx1) = v;
    }
    __syncthreads();
    const float* t = rb; rb = wb; wb = (float*)t;
  }

  // Epilogue: out = y * exp(lerp(mc[...,0])). Outputs are samples >= HALO.
  if (tid >= HALO / RPT && g0 < TT) {
    const int n1 = min(n0 + 1, NFR - 1);
    const float k0 = mcb[n0 * NC];
    const float k1 = mcb[n1 * NC];
    const float dk = (k1 - k0) * (1.0f / FP);
    float* ob = out + b * TT + g0;
    #pragma unroll
    for (int k = 0; k < 2; ++k) {
      float4 v;
      #pragma unroll
      for (int e = 0; e < 4; ++e) {
        const int j = 4 * k + e;
        const float Kg = __expf(fmaf(p0f + (float)j, dk, k0));
        ((float*)&v)[e] = y[j] * Kg;
      }
      *(float4*)(ob + 4 * k) = v;
    }
  }
}

extern "C" void kernel_launch(void* const* d_in, const int* in_sizes, int n_in,
                              void* d_out, int out_size, void* d_ws, size_t ws_size,
                              hipStream_t stream) {
  const float* x  = (const float*)d_in[0];
  const float* mc = (const float*)d_in[1];
  float* out      = (float*)d_out;
  mlsa_kernel<<<NB * TILES, NT, 0, stream>>>(x, mc, out);
}